// Round 16
// baseline (1494.393 us; speedup 1.0000x reference)
//
#include <hip/hip_runtime.h>
#include <hip/hip_bf16.h>

// RGCN layer, MI355X (gfx950).
// R16: ticketed mega-kernel. R15 post-mortem: all kernels <39us; ~15us of the 104us
// wall is launch gaps across 7 dispatches, and the edge-sort chain (~25us) is fully
// independent of gemm (~41us) yet serialized. One 5221-block dispatch; each block
// atomically grabs a ticket -> task. Order interleaves gemm tasks between sort phases;
// phases gate on device-scope done counters (release = threadfence+atomic, acquire =
// atomic+threadfence; deadlock-free: resident set always holds the min unfinished
// ticket, whose deps are lower tickets).
//   tasks: wt(16) hist(256) gemm[0,800) scan_a(782) gemm[800,1100) scan_b(1)
//          gemm[1100,1300) scatter(256) gemm[1300,1700) nsort(782) gemm[1700,3128)
// K2 k_ngather: wave-per-node rec-prefetch + shfl gather + bias + relu (merge point).
//
// ws: X 102.4MB | Wt 128KB | rec 8MB | cntT 800KB | offsT 800KB | bsum | bsum2 | noffs | ctl

#define NN 50000
#define EE 1000000
#define RR 16
#define NBLK 256            // binning blocks (hist/scatter)
#define EPB 3907            // ceil(EE/NBLK)
#define BSH 6               // 64 nodes per bucket
#define NBUK 782            // ceil(NN/64)
#define SCAP 2048           // nsort LDS record capacity (mean 1279, +21 sigma)

// ticket layout
#define T_HIST0 16
#define T_G1 272            // gemm 0..799
#define T_SCANA0 1072
#define T_G2 1854           // gemm 800..1099
#define T_SCANB 2154
#define T_G3 2155           // gemm 1100..1299
#define T_SCAT0 2355
#define T_G4 2611           // gemm 1300..1699
#define T_NSORT0 3011
#define T_G5 3793           // gemm 1700..3127
#define T_TOTAL 5221

typedef __attribute__((ext_vector_type(8))) short short8;
typedef __attribute__((ext_vector_type(4))) float f32x4;

static __device__ inline unsigned short f2bf(float f) {
  union { __hip_bfloat16 h; unsigned short u; } cv;
  cv.h = __float2bfloat16(f);
  return cv.u;
}
static __device__ inline float bf2f(unsigned short u) {
  union { unsigned i; float f; } cv;
  cv.i = ((unsigned)u) << 16;
  return cv.f;
}

static __device__ __forceinline__ void wait_ge(int* p, int n) {
  if (threadIdx.x == 0) {
    while (__hip_atomic_load(p, __ATOMIC_ACQUIRE, __HIP_MEMORY_SCOPE_AGENT) < n)
      __builtin_amdgcn_s_sleep(8);
  }
  __syncthreads();
  __threadfence();  // acquire: invalidate local L1/L2 before reading produced data
}
static __device__ __forceinline__ void mark_done(int* p) {
  __syncthreads();
  __threadfence();  // release: flush this block's stores past its XCD L2
  if (threadIdx.x == 0)
    __hip_atomic_fetch_add(p, 1, __ATOMIC_RELEASE, __HIP_MEMORY_SCOPE_AGENT);
}

// ---------------- phase bodies ----------------
static __device__ __forceinline__ void ph_wt(char* smem, int r, const float* W,
                                             unsigned short* Wt) {
  auto Wl = reinterpret_cast<unsigned short(*)[72]>(smem);
  const int tid = threadIdx.x;
  for (int i = tid; i < 4096; i += 256) Wl[i & 63][i >> 6] = f2bf(W[(r << 12) + i]);
  __syncthreads();
  const int o = tid >> 2, kc = (tid & 3) << 4;
  const short8 v0 = *reinterpret_cast<const short8*>(&Wl[o][kc]);
  const short8 v1 = *reinterpret_cast<const short8*>(&Wl[o][kc + 8]);
  unsigned short* dst = Wt + (r << 12) + (o << 6) + kc;
  *reinterpret_cast<short8*>(dst) = v0;
  *reinterpret_cast<short8*>(dst + 8) = v1;
}

static __device__ __forceinline__ void ph_hist(char* smem, int bl,
                                               const int* edst, int* cntT) {
  int* cnt = reinterpret_cast<int*>(smem);
  const int tid = threadIdx.x;
  for (int i = tid; i < NBUK; i += 256) cnt[i] = 0;
  __syncthreads();
  const int e0 = bl * EPB, e1 = min(EE, e0 + EPB);
  for (int e = e0 + tid; e < e1; e += 256) atomicAdd(&cnt[edst[e] >> BSH], 1);
  __syncthreads();
  for (int i = tid; i < NBUK; i += 256) cntT[i * NBLK + bl] = cnt[i];
}

static __device__ __forceinline__ void ph_scan_a(char* smem, int bu,
                                                 const int* cntT, int* offsT,
                                                 int* bsum) {
  int* s = reinterpret_cast<int*>(smem);
  const int t = threadIdx.x;
  const int i = bu * 256 + t;
  const int v = cntT[i];
  s[t] = v;
  __syncthreads();
  #pragma unroll
  for (int off = 1; off < 256; off <<= 1) {
    const int x = (t >= off) ? s[t - off] : 0;
    __syncthreads();
    s[t] += x;
    __syncthreads();
  }
  offsT[i] = s[t] - v;
  if (t == 255) bsum[bu] = s[255];
}

static __device__ __forceinline__ void ph_scan_b(char* smem, const int* bsum,
                                                 int* bsum2) {
  int* s = reinterpret_cast<int*>(smem);
  const int t = threadIdx.x;
  int v[4];
  int tot = 0;
  const int b4 = t << 2;
  #pragma unroll
  for (int k = 0; k < 4; ++k) {
    const int idx = b4 + k;
    v[k] = (idx < NBUK) ? bsum[idx] : 0;
    tot += v[k];
  }
  s[t] = tot;
  __syncthreads();
  #pragma unroll
  for (int off = 1; off < 256; off <<= 1) {
    const int x = (t >= off) ? s[t - off] : 0;
    __syncthreads();
    s[t] += x;
    __syncthreads();
  }
  int run = s[t] - tot;
  #pragma unroll
  for (int k = 0; k < 4; ++k) {
    const int idx = b4 + k;
    if (idx < NBUK) bsum2[idx] = run;
    run += v[k];
  }
  if (t == 0) bsum2[NBUK] = EE;
}

static __device__ __forceinline__ void ph_scatter(char* smem, int bl,
                                                  const int* esrc, const int* edst,
                                                  const int* etyp, const float* enorm,
                                                  const int* offsT, const int* bsum2,
                                                  uint2* rec) {
  int* cur = reinterpret_cast<int*>(smem);
  const int tid = threadIdx.x;
  for (int i = tid; i < NBUK; i += 256) cur[i] = offsT[i * NBLK + bl] + bsum2[i];
  __syncthreads();
  const int e0 = bl * EPB, e1 = min(EE, e0 + EPB);
  for (int e = e0 + tid; e < e1; e += 256) {
    const int d = edst[e];
    const int pos = atomicAdd(&cur[d >> BSH], 1);
    rec[pos] = make_uint2(((unsigned)(etyp[e] * NN + esrc[e]) << 6) | (unsigned)(d & 63),
                          __float_as_uint(enorm[e]));
  }
}

static __device__ __forceinline__ void ph_nsort(char* smem, int bu,
                                                const int* bsum2, uint2* rec,
                                                int* noffs) {
  uint2* sbuf = reinterpret_cast<uint2*>(smem);                   // 16384 B
  int* cnt = reinterpret_cast<int*>(smem + SCAP * 8);             //   256 B
  int* cur = reinterpret_cast<int*>(smem + SCAP * 8 + 256);       //   256 B
  const int tid = threadIdx.x;
  const int s = bsum2[bu];
  const int e = bsum2[bu + 1];
  const int n = e - s;
  if (tid < 64) cnt[tid] = 0;
  __syncthreads();
  if (n > SCAP) {  // ~impossible overflow: leave unsorted, mark for slow gather
    if (tid < 64) noffs[(bu << BSH) + tid] = -1;
    return;
  }
  for (int i = tid; i < n; i += 256) {
    const uint2 r = rec[s + i];
    sbuf[i] = r;
    atomicAdd(&cnt[r.x & 63u], 1);
  }
  __syncthreads();
  if (tid < 64) {
    const int v = cnt[tid];
    int x = v;
    #pragma unroll
    for (int off = 1; off < 64; off <<= 1) {
      const int t = __shfl_up(x, off, 64);
      if (tid >= off) x += t;
    }
    cur[tid] = x - v;
    noffs[(bu << BSH) + tid] = s + x - v;
  }
  __syncthreads();
  for (int i = tid; i < n; i += 256) {
    const uint2 r = sbuf[i];
    const int pos = atomicAdd(&cur[r.x & 63u], 1);
    rec[s + pos] = r;
  }
}

static __device__ __forceinline__ void ph_gemm(char* smem, int gi, const float* nf,
                                               const unsigned short* Wt,
                                               unsigned short* X) {
  auto Wl = reinterpret_cast<unsigned short(*)[64][72]>(smem);
  const int tid = threadIdx.x;
  const int bx = gi >> 2, r0 = (gi & 3) << 2;
  const int lane = tid & 63, wv = tid >> 6;
  const int lr = lane & 15, lg = lane >> 4;
  const int node = (bx << 6) + (wv << 4) + lr;
  #pragma unroll
  for (int rr = 0; rr < 4; ++rr) {
    const unsigned short* src = Wt + (((size_t)(r0 + rr)) << 12) + (tid << 4);
    const short8 v0 = *reinterpret_cast<const short8*>(src);
    const short8 v1 = *reinterpret_cast<const short8*>(src + 8);
    unsigned short* dst = &Wl[rr][tid >> 2][(tid & 3) << 4];
    *reinterpret_cast<short8*>(dst) = v0;
    *reinterpret_cast<short8*>(dst + 8) = v1;
  }
  short8 bf0, bf1;
  if (node < NN) {
    const float* ap = nf + (size_t)node * 64 + lg * 8;
    float4 v0 = *reinterpret_cast<const float4*>(ap);
    float4 v1 = *reinterpret_cast<const float4*>(ap + 4);
    float4 v2 = *reinterpret_cast<const float4*>(ap + 32);
    float4 v3 = *reinterpret_cast<const float4*>(ap + 36);
    bf0 = short8{(short)f2bf(v0.x), (short)f2bf(v0.y), (short)f2bf(v0.z), (short)f2bf(v0.w),
                 (short)f2bf(v1.x), (short)f2bf(v1.y), (short)f2bf(v1.z), (short)f2bf(v1.w)};
    bf1 = short8{(short)f2bf(v2.x), (short)f2bf(v2.y), (short)f2bf(v2.z), (short)f2bf(v2.w),
                 (short)f2bf(v3.x), (short)f2bf(v3.y), (short)f2bf(v3.z), (short)f2bf(v3.w)};
  } else {
    bf0 = short8{0, 0, 0, 0, 0, 0, 0, 0};
    bf1 = bf0;
  }
  __syncthreads();
  #pragma unroll
  for (int rr = 0; rr < 4; ++rr) {
    const int r = r0 + rr;
    short8 a[8];
    #pragma unroll
    for (int c = 0; c < 4; ++c) {
      a[2 * c] = *reinterpret_cast<const short8*>(&Wl[rr][(c << 4) + lr][lg << 3]);
      a[2 * c + 1] = *reinterpret_cast<const short8*>(&Wl[rr][(c << 4) + lr][32 + (lg << 3)]);
    }
    f32x4 acc[4];
    #pragma unroll
    for (int c = 0; c < 4; ++c) {
      acc[c] = f32x4{0.f, 0.f, 0.f, 0.f};
      acc[c] = __builtin_amdgcn_mfma_f32_16x16x32_bf16(a[2 * c], bf0, acc[c], 0, 0, 0);
      acc[c] = __builtin_amdgcn_mfma_f32_16x16x32_bf16(a[2 * c + 1], bf1, acc[c], 0, 0, 0);
    }
    if (node < NN) {
      #pragma unroll
      for (int c = 0; c < 4; ++c) {
        uint2 p;
        p.x = (unsigned)f2bf(acc[c][0]) | ((unsigned)f2bf(acc[c][1]) << 16);
        p.y = (unsigned)f2bf(acc[c][2]) | ((unsigned)f2bf(acc[c][3]) << 16);
        *reinterpret_cast<uint2*>(&X[((size_t)r * NN + node) * 64 + (c << 4) + (lg << 2)]) = p;
      }
    }
  }
}

// ---------------- K1: ticketed mega-kernel ----------------
// ctl[0]=ticket  ctl[1]=done_wt  ctl[2]=done_hist  ctl[3]=done_scan_a
// ctl[4]=done_scan_b  ctl[5]=done_scatter
__global__ __launch_bounds__(256) void k_mega(const float* __restrict__ nf,
                                              const float* __restrict__ W,
                                              const int* __restrict__ esrc,
                                              const int* __restrict__ edst,
                                              const int* __restrict__ etyp,
                                              const float* __restrict__ enorm,
                                              unsigned short* __restrict__ Wt,
                                              unsigned short* __restrict__ X,
                                              int* __restrict__ cntT,
                                              int* __restrict__ offsT,
                                              int* __restrict__ bsum,
                                              int* __restrict__ bsum2,
                                              uint2* __restrict__ rec,
                                              int* __restrict__ noffs,
                                              int* __restrict__ ctl) {
  __shared__ __align__(16) char smem[36864];
  __shared__ int s_ticket;
  if (threadIdx.x == 0)
    s_ticket = __hip_atomic_fetch_add(&ctl[0], 1, __ATOMIC_RELAXED, __HIP_MEMORY_SCOPE_AGENT);
  __syncthreads();
  const int T = s_ticket;
  if (T < T_HIST0) {
    ph_wt(smem, T, W, Wt);
    mark_done(&ctl[1]);
  } else if (T < T_G1) {
    ph_hist(smem, T - T_HIST0, edst, cntT);
    mark_done(&ctl[2]);
  } else if (T < T_SCANA0) {
    wait_ge(&ctl[1], RR);
    ph_gemm(smem, T - T_G1, nf, Wt, X);
  } else if (T < T_G2) {
    wait_ge(&ctl[2], NBLK);
    ph_scan_a(smem, T - T_SCANA0, cntT, offsT, bsum);
    mark_done(&ctl[3]);
  } else if (T < T_SCANB) {
    wait_ge(&ctl[1], RR);
    ph_gemm(smem, 800 + (T - T_G2), nf, Wt, X);
  } else if (T == T_SCANB) {
    wait_ge(&ctl[3], NBUK);
    ph_scan_b(smem, bsum, bsum2);
    mark_done(&ctl[4]);
  } else if (T < T_SCAT0) {
    wait_ge(&ctl[1], RR);
    ph_gemm(smem, 1100 + (T - T_G3), nf, Wt, X);
  } else if (T < T_G4) {
    wait_ge(&ctl[4], 1);
    ph_scatter(smem, T - T_SCAT0, esrc, edst, etyp, enorm, offsT, bsum2, rec);
    mark_done(&ctl[5]);
  } else if (T < T_NSORT0) {
    wait_ge(&ctl[1], RR);
    ph_gemm(smem, 1300 + (T - T_G4), nf, Wt, X);
  } else if (T < T_G5) {
    wait_ge(&ctl[5], NBLK);
    ph_nsort(smem, T - T_NSORT0, bsum2, rec, noffs);
  } else {
    wait_ge(&ctl[1], RR);
    ph_gemm(smem, 1700 + (T - T_G5), nf, Wt, X);
  }
}

// ---------------- K2: wave-per-node gather, rec-prefetch + shfl ----------------
__global__ __launch_bounds__(256) void k_ngather(const uint2* __restrict__ rec,
                                                 const int* __restrict__ noffs,
                                                 const int* __restrict__ bsum2,
                                                 const unsigned short* __restrict__ X,
                                                 const float* __restrict__ bias,
                                                 float* __restrict__ out) {
  const int w = (int)((blockIdx.x * 256 + threadIdx.x) >> 6);  // node id
  const int lane = threadIdx.x & 63;
  if (w >= NN) return;
  const int quarter = lane >> 4, d4 = lane & 15;
  const int bu = w >> BSH;
  float4 acc = {0.f, 0.f, 0.f, 0.f};
  const int jb = noffs[w];
  if (jb >= 0) {
    const int je = ((w & 63) == 63) ? bsum2[bu + 1] : noffs[w + 1];
    for (int base = jb; base < je; base += 64) {
      const int deg = min(64, je - base);
      unsigned rxs = 0;
      float rns = 0.f;
      if (lane < deg) {
        const uint2 r = rec[base + lane];
        rxs = r.x >> 6;
        rns = __uint_as_float(r.y);
      }
      int u = 0;
      for (; u + 16 <= deg; u += 16) {  // 16 edges per body, 4 independent X loads
        unsigned row[4];
        float nm[4];
        uint2 xv[4];
        #pragma unroll
        for (int k = 0; k < 4; ++k) {
          const int i = u + 4 * k + quarter;
          row[k] = (unsigned)__shfl((int)rxs, i, 64);
          nm[k] = __shfl(rns, i, 64);
        }
        #pragma unroll
        for (int k = 0; k < 4; ++k)
          xv[k] = *reinterpret_cast<const uint2*>(X + (size_t)row[k] * 64 + (d4 << 2));
        #pragma unroll
        for (int k = 0; k < 4; ++k) {
          acc.x = fmaf(nm[k], bf2f((unsigned short)(xv[k].x & 0xffffu)), acc.x);
          acc.y = fmaf(nm[k], bf2f((unsigned short)(xv[k].x >> 16)), acc.y);
          acc.z = fmaf(nm[k], bf2f((unsigned short)(xv[k].y & 0xffffu)), acc.z);
          acc.w = fmaf(nm[k], bf2f((unsigned short)(xv[k].y >> 16)), acc.w);
        }
      }
      for (; u + 8 <= deg; u += 8) {
        const int i0 = u + quarter, i1 = u + 4 + quarter;
        const unsigned row0 = (unsigned)__shfl((int)rxs, i0, 64);
        const float n0 = __shfl(rns, i0, 64);
        const unsigned row1 = (unsigned)__shfl((int)rxs, i1, 64);
        const float n1 = __shfl(rns, i1, 64);
        const uint2 x0 = *reinterpret_cast<const uint2*>(X + (size_t)row0 * 64 + (d4 << 2));
        const uint2 x1 = *reinterpret_cast<const uint2*>(X + (size_t)row1 * 64 + (d4 << 2));
        acc.x = fmaf(n0, bf2f((unsigned short)(x0.x & 0xffffu)), acc.x);
        acc.y = fmaf(n0, bf2f((unsigned short)(x0.x >> 16)), acc.y);
        acc.z = fmaf(n0, bf2f((unsigned short)(x0.y & 0xffffu)), acc.z);
        acc.w = fmaf(n0, bf2f((unsigned short)(x0.y >> 16)), acc.w);
        acc.x = fmaf(n1, bf2f((unsigned short)(x1.x & 0xffffu)), acc.x);
        acc.y = fmaf(n1, bf2f((unsigned short)(x1.x >> 16)), acc.y);
        acc.z = fmaf(n1, bf2f((unsigned short)(x1.y & 0xffffu)), acc.z);
        acc.w = fmaf(n1, bf2f((unsigned short)(x1.y >> 16)), acc.w);
      }
      for (; u < deg; u += 4) {
        const int i = u + quarter;
        const int ic = min(i, deg - 1);
        const unsigned row = (unsigned)__shfl((int)rxs, ic, 64);
        float n = __shfl(rns, ic, 64);
        n = (i < deg) ? n : 0.f;
        const uint2 x = *reinterpret_cast<const uint2*>(X + (size_t)row * 64 + (d4 << 2));
        acc.x = fmaf(n, bf2f((unsigned short)(x.x & 0xffffu)), acc.x);
        acc.y = fmaf(n, bf2f((unsigned short)(x.x >> 16)), acc.y);
        acc.z = fmaf(n, bf2f((unsigned short)(x.y & 0xffffu)), acc.z);
        acc.w = fmaf(n, bf2f((unsigned short)(x.y >> 16)), acc.w);
      }
    }
  } else {
    if (quarter == 0) {
      const int s = bsum2[bu];
      const int e = bsum2[bu + 1];
      const unsigned dl = (unsigned)(w & 63);
      for (int j = s; j < e; ++j) {
        const uint2 r = rec[j];
        if ((r.x & 63u) == dl) {
          const float n = __uint_as_float(r.y);
          const uint2 x =
              *reinterpret_cast<const uint2*>(X + (size_t)(r.x >> 6) * 64 + (d4 << 2));
          acc.x = fmaf(n, bf2f((unsigned short)(x.x & 0xffffu)), acc.x);
          acc.y = fmaf(n, bf2f((unsigned short)(x.x >> 16)), acc.y);
          acc.z = fmaf(n, bf2f((unsigned short)(x.y & 0xffffu)), acc.z);
          acc.w = fmaf(n, bf2f((unsigned short)(x.y >> 16)), acc.w);
        }
      }
    }
  }
  acc.x += __shfl_xor(acc.x, 16, 64);
  acc.y += __shfl_xor(acc.y, 16, 64);
  acc.z += __shfl_xor(acc.z, 16, 64);
  acc.w += __shfl_xor(acc.w, 16, 64);
  acc.x += __shfl_xor(acc.x, 32, 64);
  acc.y += __shfl_xor(acc.y, 32, 64);
  acc.z += __shfl_xor(acc.z, 32, 64);
  acc.w += __shfl_xor(acc.w, 32, 64);
  if (quarter == 0) {
    const float4 b = reinterpret_cast<const float4*>(bias)[d4];
    float4 o;
    o.x = fmaxf(acc.x + b.x, 0.f);
    o.y = fmaxf(acc.y + b.y, 0.f);
    o.z = fmaxf(acc.z + b.z, 0.f);
    o.w = fmaxf(acc.w + b.w, 0.f);
    reinterpret_cast<float4*>(out)[(size_t)w * 16 + d4] = o;
  }
}

extern "C" void kernel_launch(void* const* d_in, const int* in_sizes, int n_in,
                              void* d_out, int out_size, void* d_ws, size_t ws_size,
                              hipStream_t stream) {
  const float* nf = (const float*)d_in[0];
  const int* esrc = (const int*)d_in[1];
  const int* edst = (const int*)d_in[2];
  const int* etyp = (const int*)d_in[3];
  const float* enorm = (const float*)d_in[4];
  const float* W = (const float*)d_in[5];
  const float* bias = (const float*)d_in[6];
  float* out = (float*)d_out;

  char* ws = (char*)d_ws;
  unsigned short* X = (unsigned short*)ws;                 // 102,400,000 B
  unsigned short* Wt = (unsigned short*)(ws + 102400000);  //     131,072 B
  uint2* rec = (uint2*)(ws + 102531072);                   //   8,000,000 B
  int* cntT = (int*)(ws + 110531072);                      //     800,768 B
  int* offsT = (int*)(ws + 111331840);                     //     800,768 B
  int* bsum = (int*)(ws + 112132608);                      //       3,128 B
  int* bsum2 = (int*)(ws + 112135736);                     //       3,132 B
  int* noffs = (int*)(ws + 112138868);                     //     200,192 B
  int* ctl = (int*)(ws + 112339072);                       //          24 B

  hipMemsetAsync(ctl, 0, 24, stream);
  k_mega<<<T_TOTAL, 256, 0, stream>>>(nf, W, esrc, edst, etyp, enorm, Wt, X, cntT,
                                      offsT, bsum, bsum2, rec, noffs, ctl);
  k_ngather<<<(NN * 64 + 255) / 256, 256, 0, stream>>>(rec, noffs, bsum2, X, bias, out);
}

// Round 17
// 112.090 us; speedup vs baseline: 13.3321x; 13.3321x over previous
//
#include <hip/hip_runtime.h>
#include <hip/hip_bf16.h>

// RGCN layer, MI355X (gfx950).
// R17 = R15 base (R16 post-mortem: persistent-ticket mega-kernel = 14x regression,
// spin-gate convoys at 0.4% VALU; hard revert) + algebraic scan elimination:
//  - k_wthist: hist blocks get their in-bucket range start from atomicAdd(&gcnt[b],cnt)
//    (block order within bucket irrelevant -- nsort re-sorts) -> scan_a DELETED.
//  - k_scatter: each block redundantly scans gcnt[782] in LDS (cheap, parallel);
//    block 0 publishes bsum2 for nsort/ngather -> scan_b DELETED.
//  7 dispatches -> 5.
//  K0 k_wthist | K1 k_gemm (R11-verbatim, ~3.2TB/s write wall) | K2 k_scatter |
//  K3 k_nsort | K4 k_ngather (rec-prefetch + shfl, unroll-4).
//
// ws: X 102.4MB | Wt 128KB | rec 8MB | blkoff 800KB | gcnt 3.1KB | bsum2 3.1KB | noffs 200KB

#define NN 50000
#define EE 1000000
#define RR 16
#define NBLK 256            // binning blocks (hist/scatter)
#define EPB 3907            // ceil(EE/NBLK)
#define BSH 6               // 64 nodes per bucket
#define NBUK 782            // ceil(NN/64)
#define SCAP 2048           // nsort LDS record capacity (mean 1279, +21 sigma)

typedef __attribute__((ext_vector_type(8))) short short8;
typedef __attribute__((ext_vector_type(4))) float f32x4;

static __device__ inline unsigned short f2bf(float f) {
  union { __hip_bfloat16 h; unsigned short u; } cv;
  cv.h = __float2bfloat16(f);
  return cv.u;
}
static __device__ inline float bf2f(unsigned short u) {
  union { unsigned i; float f; } cv;
  cv.i = ((unsigned)u) << 16;
  return cv.f;
}

// ---------------- K0: fused one-time W transpose + edge histogram ----------------
// Blocks [0,RR): W[r][k][o] fp32 -> Wt[r][o][k] bf16.
// Blocks [RR, RR+NBLK): per-block bucket histogram; block's range start within each
// bucket = atomicAdd(&gcnt[bucket], count) (unordered, disjoint -> correct).
__global__ __launch_bounds__(256) void k_wthist(const float* __restrict__ W,
                                                const int* __restrict__ edst,
                                                unsigned short* __restrict__ Wt,
                                                int* __restrict__ gcnt,
                                                int* __restrict__ blkoff) {
  __shared__ __align__(16) char smem[64 * 72 * 2];  // 9216 B union
  const int bid = blockIdx.x, tid = threadIdx.x;
  if (bid < RR) {
    auto Wl = reinterpret_cast<unsigned short(*)[72]>(smem);
    const int r = bid;
    for (int i = tid; i < 4096; i += 256) Wl[i & 63][i >> 6] = f2bf(W[(r << 12) + i]);
    __syncthreads();
    const int o = tid >> 2, kc = (tid & 3) << 4;
    const short8 v0 = *reinterpret_cast<const short8*>(&Wl[o][kc]);
    const short8 v1 = *reinterpret_cast<const short8*>(&Wl[o][kc + 8]);
    unsigned short* dst = Wt + (r << 12) + (o << 6) + kc;
    *reinterpret_cast<short8*>(dst) = v0;
    *reinterpret_cast<short8*>(dst + 8) = v1;
    return;
  }
  int* cnt = reinterpret_cast<int*>(smem);  // 782*4 = 3128 B <= 9216 B
  const int bl = bid - RR;
  for (int i = tid; i < NBUK; i += 256) cnt[i] = 0;
  __syncthreads();
  const int e0 = bl * EPB, e1 = min(EE, e0 + EPB);
  for (int e = e0 + tid; e < e1; e += 256) atomicAdd(&cnt[edst[e] >> BSH], 1);
  __syncthreads();
  for (int i = tid; i < NBUK; i += 256) {
    const int c = cnt[i];
    blkoff[i * NBLK + bl] = c ? atomicAdd(&gcnt[i], c) : 0;
  }
}

// ---------------- K1: dense transform (R11-verbatim, at the write wall) ----------------
__global__ __launch_bounds__(256) void k_gemm(const float* __restrict__ nf,
                                              const unsigned short* __restrict__ Wt,
                                              unsigned short* __restrict__ X) {
  __shared__ __align__(16) unsigned short Wl[4][64][72];  // 36,864 B
  const int tid = threadIdx.x;
  const int lane = tid & 63, wv = tid >> 6;
  const int lr = lane & 15, lg = lane >> 4;
  const int node = (blockIdx.x << 6) + (wv << 4) + lr;
  const int r0 = blockIdx.y << 2;
  #pragma unroll
  for (int rr = 0; rr < 4; ++rr) {
    const unsigned short* src = Wt + (((size_t)(r0 + rr)) << 12) + (tid << 4);
    const short8 v0 = *reinterpret_cast<const short8*>(src);
    const short8 v1 = *reinterpret_cast<const short8*>(src + 8);
    unsigned short* dst = &Wl[rr][tid >> 2][(tid & 3) << 4];
    *reinterpret_cast<short8*>(dst) = v0;
    *reinterpret_cast<short8*>(dst + 8) = v1;
  }
  short8 bf0, bf1;
  if (node < NN) {
    const float* ap = nf + (size_t)node * 64 + lg * 8;
    float4 v0 = *reinterpret_cast<const float4*>(ap);
    float4 v1 = *reinterpret_cast<const float4*>(ap + 4);
    float4 v2 = *reinterpret_cast<const float4*>(ap + 32);
    float4 v3 = *reinterpret_cast<const float4*>(ap + 36);
    bf0 = short8{(short)f2bf(v0.x), (short)f2bf(v0.y), (short)f2bf(v0.z), (short)f2bf(v0.w),
                 (short)f2bf(v1.x), (short)f2bf(v1.y), (short)f2bf(v1.z), (short)f2bf(v1.w)};
    bf1 = short8{(short)f2bf(v2.x), (short)f2bf(v2.y), (short)f2bf(v2.z), (short)f2bf(v2.w),
                 (short)f2bf(v3.x), (short)f2bf(v3.y), (short)f2bf(v3.z), (short)f2bf(v3.w)};
  } else {
    bf0 = short8{0, 0, 0, 0, 0, 0, 0, 0};
    bf1 = bf0;
  }
  __syncthreads();
  #pragma unroll
  for (int rr = 0; rr < 4; ++rr) {
    const int r = r0 + rr;
    short8 a[8];
    #pragma unroll
    for (int c = 0; c < 4; ++c) {
      a[2 * c] = *reinterpret_cast<const short8*>(&Wl[rr][(c << 4) + lr][lg << 3]);
      a[2 * c + 1] = *reinterpret_cast<const short8*>(&Wl[rr][(c << 4) + lr][32 + (lg << 3)]);
    }
    f32x4 acc[4];
    #pragma unroll
    for (int c = 0; c < 4; ++c) {
      acc[c] = f32x4{0.f, 0.f, 0.f, 0.f};
      acc[c] = __builtin_amdgcn_mfma_f32_16x16x32_bf16(a[2 * c], bf0, acc[c], 0, 0, 0);
      acc[c] = __builtin_amdgcn_mfma_f32_16x16x32_bf16(a[2 * c + 1], bf1, acc[c], 0, 0, 0);
    }
    if (node < NN) {
      #pragma unroll
      for (int c = 0; c < 4; ++c) {
        uint2 p;
        p.x = (unsigned)f2bf(acc[c][0]) | ((unsigned)f2bf(acc[c][1]) << 16);
        p.y = (unsigned)f2bf(acc[c][2]) | ((unsigned)f2bf(acc[c][3]) << 16);
        *reinterpret_cast<uint2*>(&X[((size_t)r * NN + node) * 64 + (c << 4) + (lg << 2)]) = p;
      }
    }
  }
}

// ---------------- K2: scatter with in-LDS bucket-start scan ----------------
// Each block: chunked 256-thread scan of gcnt[782] -> bucket global starts (bloc);
// block 0 publishes bsum2 for downstream kernels. cur = bloc + blkoff(this block).
__global__ __launch_bounds__(256) void k_scatter(const int* __restrict__ esrc,
                                                 const int* __restrict__ edst,
                                                 const int* __restrict__ etyp,
                                                 const float* __restrict__ enorm,
                                                 const int* __restrict__ gcnt,
                                                 const int* __restrict__ blkoff,
                                                 int* __restrict__ bsum2,
                                                 uint2* __restrict__ rec) {
  __shared__ int bloc[NBUK];
  __shared__ int s[256];
  __shared__ int cur[NBUK];
  const int bl = blockIdx.x, t = threadIdx.x;
  // chunked exclusive scan: thread t owns buckets 4t..4t+3
  int v[4];
  int tot = 0;
  const int b4 = t << 2;
  #pragma unroll
  for (int k = 0; k < 4; ++k) {
    const int idx = b4 + k;
    v[k] = (idx < NBUK) ? gcnt[idx] : 0;
    tot += v[k];
  }
  s[t] = tot;
  __syncthreads();
  #pragma unroll
  for (int off = 1; off < 256; off <<= 1) {
    const int x = (t >= off) ? s[t - off] : 0;
    __syncthreads();
    s[t] += x;
    __syncthreads();
  }
  int run = s[t] - tot;
  #pragma unroll
  for (int k = 0; k < 4; ++k) {
    const int idx = b4 + k;
    if (idx < NBUK) bloc[idx] = run;
    run += v[k];
  }
  __syncthreads();
  if (bl == 0) {  // publish for nsort/ngather
    for (int i = t; i < NBUK; i += 256) bsum2[i] = bloc[i];
    if (t == 0) bsum2[NBUK] = EE;
  }
  for (int i = t; i < NBUK; i += 256) cur[i] = bloc[i] + blkoff[i * NBLK + bl];
  __syncthreads();
  const int e0 = bl * EPB, e1 = min(EE, e0 + EPB);
  for (int e = e0 + t; e < e1; e += 256) {
    const int d = edst[e];
    const int pos = atomicAdd(&cur[d >> BSH], 1);
    // pack: (typ*NN+src)<<6 | dstlow  (r.x>>6 == X row id, typ-major layout)
    rec[pos] = make_uint2(((unsigned)(etyp[e] * NN + esrc[e]) << 6) | (unsigned)(d & 63),
                          __float_as_uint(enorm[e]));
  }
}

// ---------------- K3: in-bucket sort by exact dst node (in place) ----------------
__global__ __launch_bounds__(256) void k_nsort(const int* __restrict__ bsum2,
                                               uint2* __restrict__ rec,
                                               int* __restrict__ noffs) {
  __shared__ uint2 sbuf[SCAP];  // 16 KB
  __shared__ int cnt[64], cur[64];
  const int bu = blockIdx.x, tid = threadIdx.x;
  const int s = bsum2[bu];
  const int e = bsum2[bu + 1];
  const int n = e - s;
  if (tid < 64) cnt[tid] = 0;
  __syncthreads();
  if (n > SCAP) {  // ~impossible overflow: leave unsorted, mark for slow gather
    if (tid < 64) noffs[(bu << BSH) + tid] = -1;
    return;
  }
  for (int i = tid; i < n; i += 256) {
    const uint2 r = rec[s + i];
    sbuf[i] = r;
    atomicAdd(&cnt[r.x & 63u], 1);
  }
  __syncthreads();
  if (tid < 64) {
    const int v = cnt[tid];
    int x = v;
    #pragma unroll
    for (int off = 1; off < 64; off <<= 1) {
      const int t = __shfl_up(x, off, 64);
      if (tid >= off) x += t;
    }
    cur[tid] = x - v;
    noffs[(bu << BSH) + tid] = s + x - v;
  }
  __syncthreads();
  for (int i = tid; i < n; i += 256) {
    const uint2 r = sbuf[i];
    const int pos = atomicAdd(&cur[r.x & 63u], 1);
    rec[s + pos] = r;
  }
}

// ---------------- K4: wave-per-node gather, rec-prefetch + shfl, unroll-4 ----------------
__global__ __launch_bounds__(256) void k_ngather(const uint2* __restrict__ rec,
                                                 const int* __restrict__ noffs,
                                                 const int* __restrict__ bsum2,
                                                 const unsigned short* __restrict__ X,
                                                 const float* __restrict__ bias,
                                                 float* __restrict__ out) {
  const int w = (int)((blockIdx.x * 256 + threadIdx.x) >> 6);  // node id
  const int lane = threadIdx.x & 63;
  if (w >= NN) return;
  const int quarter = lane >> 4, d4 = lane & 15;
  const int bu = w >> BSH;
  float4 acc = {0.f, 0.f, 0.f, 0.f};
  const int jb = noffs[w];
  if (jb >= 0) {
    const int je = ((w & 63) == 63) ? bsum2[bu + 1] : noffs[w + 1];
    for (int base = jb; base < je; base += 64) {
      const int deg = min(64, je - base);
      unsigned rxs = 0;
      float rns = 0.f;
      if (lane < deg) {
        const uint2 r = rec[base + lane];
        rxs = r.x >> 6;
        rns = __uint_as_float(r.y);
      }
      int u = 0;
      for (; u + 16 <= deg; u += 16) {  // 16 edges per body, 4 independent X loads
        unsigned row[4];
        float nm[4];
        uint2 xv[4];
        #pragma unroll
        for (int k = 0; k < 4; ++k) {
          const int i = u + 4 * k + quarter;
          row[k] = (unsigned)__shfl((int)rxs, i, 64);
          nm[k] = __shfl(rns, i, 64);
        }
        #pragma unroll
        for (int k = 0; k < 4; ++k)
          xv[k] = *reinterpret_cast<const uint2*>(X + (size_t)row[k] * 64 + (d4 << 2));
        #pragma unroll
        for (int k = 0; k < 4; ++k) {
          acc.x = fmaf(nm[k], bf2f((unsigned short)(xv[k].x & 0xffffu)), acc.x);
          acc.y = fmaf(nm[k], bf2f((unsigned short)(xv[k].x >> 16)), acc.y);
          acc.z = fmaf(nm[k], bf2f((unsigned short)(xv[k].y & 0xffffu)), acc.z);
          acc.w = fmaf(nm[k], bf2f((unsigned short)(xv[k].y >> 16)), acc.w);
        }
      }
      for (; u + 8 <= deg; u += 8) {
        const int i0 = u + quarter, i1 = u + 4 + quarter;
        const unsigned row0 = (unsigned)__shfl((int)rxs, i0, 64);
        const float n0 = __shfl(rns, i0, 64);
        const unsigned row1 = (unsigned)__shfl((int)rxs, i1, 64);
        const float n1 = __shfl(rns, i1, 64);
        const uint2 x0 = *reinterpret_cast<const uint2*>(X + (size_t)row0 * 64 + (d4 << 2));
        const uint2 x1 = *reinterpret_cast<const uint2*>(X + (size_t)row1 * 64 + (d4 << 2));
        acc.x = fmaf(n0, bf2f((unsigned short)(x0.x & 0xffffu)), acc.x);
        acc.y = fmaf(n0, bf2f((unsigned short)(x0.x >> 16)), acc.y);
        acc.z = fmaf(n0, bf2f((unsigned short)(x0.y & 0xffffu)), acc.z);
        acc.w = fmaf(n0, bf2f((unsigned short)(x0.y >> 16)), acc.w);
        acc.x = fmaf(n1, bf2f((unsigned short)(x1.x & 0xffffu)), acc.x);
        acc.y = fmaf(n1, bf2f((unsigned short)(x1.x >> 16)), acc.y);
        acc.z = fmaf(n1, bf2f((unsigned short)(x1.y & 0xffffu)), acc.z);
        acc.w = fmaf(n1, bf2f((unsigned short)(x1.y >> 16)), acc.w);
      }
      for (; u < deg; u += 4) {
        const int i = u + quarter;
        const int ic = min(i, deg - 1);
        const unsigned row = (unsigned)__shfl((int)rxs, ic, 64);
        float n = __shfl(rns, ic, 64);
        n = (i < deg) ? n : 0.f;
        const uint2 x = *reinterpret_cast<const uint2*>(X + (size_t)row * 64 + (d4 << 2));
        acc.x = fmaf(n, bf2f((unsigned short)(x.x & 0xffffu)), acc.x);
        acc.y = fmaf(n, bf2f((unsigned short)(x.x >> 16)), acc.y);
        acc.z = fmaf(n, bf2f((unsigned short)(x.y & 0xffffu)), acc.z);
        acc.w = fmaf(n, bf2f((unsigned short)(x.y >> 16)), acc.w);
      }
    }
  } else {
    if (quarter == 0) {
      const int s = bsum2[bu];
      const int e = bsum2[bu + 1];
      const unsigned dl = (unsigned)(w & 63);
      for (int j = s; j < e; ++j) {
        const uint2 r = rec[j];
        if ((r.x & 63u) == dl) {
          const float n = __uint_as_float(r.y);
          const uint2 x =
              *reinterpret_cast<const uint2*>(X + (size_t)(r.x >> 6) * 64 + (d4 << 2));
          acc.x = fmaf(n, bf2f((unsigned short)(x.x & 0xffffu)), acc.x);
          acc.y = fmaf(n, bf2f((unsigned short)(x.x >> 16)), acc.y);
          acc.z = fmaf(n, bf2f((unsigned short)(x.y & 0xffffu)), acc.z);
          acc.w = fmaf(n, bf2f((unsigned short)(x.y >> 16)), acc.w);
        }
      }
    }
  }
  acc.x += __shfl_xor(acc.x, 16, 64);
  acc.y += __shfl_xor(acc.y, 16, 64);
  acc.z += __shfl_xor(acc.z, 16, 64);
  acc.w += __shfl_xor(acc.w, 16, 64);
  acc.x += __shfl_xor(acc.x, 32, 64);
  acc.y += __shfl_xor(acc.y, 32, 64);
  acc.z += __shfl_xor(acc.z, 32, 64);
  acc.w += __shfl_xor(acc.w, 32, 64);
  if (quarter == 0) {
    const float4 b = reinterpret_cast<const float4*>(bias)[d4];
    float4 o;
    o.x = fmaxf(acc.x + b.x, 0.f);
    o.y = fmaxf(acc.y + b.y, 0.f);
    o.z = fmaxf(acc.z + b.z, 0.f);
    o.w = fmaxf(acc.w + b.w, 0.f);
    reinterpret_cast<float4*>(out)[(size_t)w * 16 + d4] = o;
  }
}

extern "C" void kernel_launch(void* const* d_in, const int* in_sizes, int n_in,
                              void* d_out, int out_size, void* d_ws, size_t ws_size,
                              hipStream_t stream) {
  const float* nf = (const float*)d_in[0];
  const int* esrc = (const int*)d_in[1];
  const int* edst = (const int*)d_in[2];
  const int* etyp = (const int*)d_in[3];
  const float* enorm = (const float*)d_in[4];
  const float* W = (const float*)d_in[5];
  const float* bias = (const float*)d_in[6];
  float* out = (float*)d_out;

  char* ws = (char*)d_ws;
  unsigned short* X = (unsigned short*)ws;                 // 102,400,000 B
  unsigned short* Wt = (unsigned short*)(ws + 102400000);  //     131,072 B
  uint2* rec = (uint2*)(ws + 102531072);                   //   8,000,000 B
  int* blkoff = (int*)(ws + 110531072);                    //     800,768 B
  int* gcnt = (int*)(ws + 111331840);                      //       3,128 B
  int* bsum2 = (int*)(ws + 111334968);                     //       3,132 B
  int* noffs = (int*)(ws + 111338100);                     //     200,192 B

  hipMemsetAsync(gcnt, 0, NBUK * 4, stream);
  k_wthist<<<RR + NBLK, 256, 0, stream>>>(W, edst, Wt, gcnt, blkoff);
  dim3 g1(NBUK, 4);
  k_gemm<<<g1, 256, 0, stream>>>(nf, Wt, X);
  k_scatter<<<NBLK, 256, 0, stream>>>(esrc, edst, etyp, enorm, gcnt, blkoff, bsum2, rec);
  k_nsort<<<NBUK, 256, 0, stream>>>(bsum2, rec, noffs);
  k_ngather<<<(NN * 64 + 255) / 256, 256, 0, stream>>>(rec, noffs, bsum2, X, bias, out);
}

// Round 18
// 102.079 us; speedup vs baseline: 14.6396x; 1.0981x over previous
//
#include <hip/hip_runtime.h>
#include <hip/hip_bf16.h>

// RGCN layer, MI355X (gfx950).
// R18 = R14 exact revert (best measured: 103.19us) + R15's unroll-4 ngather body.
// R17 post-mortem: scan-elimination + memset dispatch cost +9us vs R14's
// hist-writes-counts + two tiny scans (no memset). R16: persistent tickets = 14x
// regression. Structure frozen:
//  K0 k_wt: W[r][k][o] fp32 -> Wt[r][o][k] bf16, one-time, 16 blocks.
//  K1 k_gemm_hist: blocks 0..255 = edge histogram; blocks 256.. = gemm
//     (256 thr, 64 nodes x 4 rels, LDS Wt via two short8/thread, ~3.2TB/s write wall).
//  K2 k_scan_a: per-bucket scan of 256 per-block counts.
//  K3 k_scan_b: scan 782 bucket totals -> bsum2 global bucket starts.
//  K4 k_scatter: private counting-sort scatter (cursor = offsT_raw + bsum2).
//  K5 k_nsort: in-bucket sort by exact dst node -> per-node CSR noffs.
//  K6 k_ngather: wave-per-node rec-prefetch + shfl broadcast, unroll-4.
//
// ws: X 102.4MB | Wt 128KB | rec 8MB | cntT 800KB | offsT 800KB | bsum | bsum2 | noffs

#define NN 50000
#define EE 1000000
#define RR 16
#define NBLK 256            // binning blocks (hist/scatter)
#define EPB 3907            // ceil(EE/NBLK)
#define BSH 6               // 64 nodes per bucket
#define NBUK 782            // ceil(NN/64)
#define NS (NBUK * NBLK)    // 200192
#define SCAP 2048           // k_nsort LDS record capacity (mean 1279, +21 sigma)

typedef __attribute__((ext_vector_type(8))) short short8;
typedef __attribute__((ext_vector_type(4))) float f32x4;

static __device__ inline unsigned short f2bf(float f) {
  union { __hip_bfloat16 h; unsigned short u; } cv;
  cv.h = __float2bfloat16(f);
  return cv.u;
}
static __device__ inline float bf2f(unsigned short u) {
  union { unsigned i; float f; } cv;
  cv.i = ((unsigned)u) << 16;
  return cv.f;
}

// ---------------- K0: W[r][k][o] fp32 -> Wt[r][o][k] bf16 (one-time) ----------------
__global__ __launch_bounds__(256) void k_wt(const float* __restrict__ W,
                                            unsigned short* __restrict__ Wt) {
  __shared__ __align__(16) unsigned short Wl[64][72];
  const int r = blockIdx.x, tid = threadIdx.x;
  for (int i = tid; i < 4096; i += 256) Wl[i & 63][i >> 6] = f2bf(W[(r << 12) + i]);
  __syncthreads();
  const int o = tid >> 2, kc = (tid & 3) << 4;
  const short8 v0 = *reinterpret_cast<const short8*>(&Wl[o][kc]);
  const short8 v1 = *reinterpret_cast<const short8*>(&Wl[o][kc + 8]);
  unsigned short* dst = Wt + (r << 12) + (o << 6) + kc;
  *reinterpret_cast<short8*>(dst) = v0;
  *reinterpret_cast<short8*>(dst + 8) = v1;
}

// ---------------- K1: fused edge-histogram + dense transform ----------------
__global__ __launch_bounds__(256) void k_gemm_hist(const float* __restrict__ nf,
                                                   const unsigned short* __restrict__ Wt,
                                                   const int* __restrict__ edst,
                                                   unsigned short* __restrict__ X,
                                                   int* __restrict__ cntT) {
  __shared__ __align__(16) char smem[4 * 64 * 72 * 2];  // 36,864 B union
  const int bid = blockIdx.x, tid = threadIdx.x;
  if (bid < NBLK) {
    // ---- histogram path ----
    int* cnt = reinterpret_cast<int*>(smem);
    for (int i = tid; i < NBUK; i += 256) cnt[i] = 0;
    __syncthreads();
    const int e0 = bid * EPB, e1 = min(EE, e0 + EPB);
    for (int e = e0 + tid; e < e1; e += 256) atomicAdd(&cnt[edst[e] >> BSH], 1);
    __syncthreads();
    for (int i = tid; i < NBUK; i += 256) cntT[i * NBLK + bid] = cnt[i];
    return;
  }
  // ---- gemm path ----
  auto Wl = reinterpret_cast<unsigned short(*)[64][72]>(smem);
  const int g = bid - NBLK;
  const int bx = g >> 2, r0 = (g & 3) << 2;
  const int lane = tid & 63, wv = tid >> 6;
  const int lr = lane & 15, lg = lane >> 4;
  const int node = (bx << 6) + (wv << 4) + lr;
  #pragma unroll
  for (int rr = 0; rr < 4; ++rr) {
    const unsigned short* src = Wt + (((size_t)(r0 + rr)) << 12) + (tid << 4);
    const short8 v0 = *reinterpret_cast<const short8*>(src);
    const short8 v1 = *reinterpret_cast<const short8*>(src + 8);
    unsigned short* dst = &Wl[rr][tid >> 2][(tid & 3) << 4];
    *reinterpret_cast<short8*>(dst) = v0;
    *reinterpret_cast<short8*>(dst + 8) = v1;
  }
  short8 bf0, bf1;
  if (node < NN) {
    const float* ap = nf + (size_t)node * 64 + lg * 8;
    float4 v0 = *reinterpret_cast<const float4*>(ap);
    float4 v1 = *reinterpret_cast<const float4*>(ap + 4);
    float4 v2 = *reinterpret_cast<const float4*>(ap + 32);
    float4 v3 = *reinterpret_cast<const float4*>(ap + 36);
    bf0 = short8{(short)f2bf(v0.x), (short)f2bf(v0.y), (short)f2bf(v0.z), (short)f2bf(v0.w),
                 (short)f2bf(v1.x), (short)f2bf(v1.y), (short)f2bf(v1.z), (short)f2bf(v1.w)};
    bf1 = short8{(short)f2bf(v2.x), (short)f2bf(v2.y), (short)f2bf(v2.z), (short)f2bf(v2.w),
                 (short)f2bf(v3.x), (short)f2bf(v3.y), (short)f2bf(v3.z), (short)f2bf(v3.w)};
  } else {
    bf0 = short8{0, 0, 0, 0, 0, 0, 0, 0};
    bf1 = bf0;
  }
  __syncthreads();
  #pragma unroll
  for (int rr = 0; rr < 4; ++rr) {
    const int r = r0 + rr;
    short8 a[8];
    #pragma unroll
    for (int c = 0; c < 4; ++c) {
      a[2 * c] = *reinterpret_cast<const short8*>(&Wl[rr][(c << 4) + lr][lg << 3]);
      a[2 * c + 1] = *reinterpret_cast<const short8*>(&Wl[rr][(c << 4) + lr][32 + (lg << 3)]);
    }
    f32x4 acc[4];
    #pragma unroll
    for (int c = 0; c < 4; ++c) {
      acc[c] = f32x4{0.f, 0.f, 0.f, 0.f};
      acc[c] = __builtin_amdgcn_mfma_f32_16x16x32_bf16(a[2 * c], bf0, acc[c], 0, 0, 0);
      acc[c] = __builtin_amdgcn_mfma_f32_16x16x32_bf16(a[2 * c + 1], bf1, acc[c], 0, 0, 0);
    }
    if (node < NN) {
      #pragma unroll
      for (int c = 0; c < 4; ++c) {
        uint2 p;
        p.x = (unsigned)f2bf(acc[c][0]) | ((unsigned)f2bf(acc[c][1]) << 16);
        p.y = (unsigned)f2bf(acc[c][2]) | ((unsigned)f2bf(acc[c][3]) << 16);
        *reinterpret_cast<uint2*>(&X[((size_t)r * NN + node) * 64 + (c << 4) + (lg << 2)]) = p;
      }
    }
  }
}

// ---------------- K2: per-bucket scan of per-block counts ----------------
__global__ __launch_bounds__(256) void k_scan_a(const int* __restrict__ cntT,
                                                int* __restrict__ offsT,
                                                int* __restrict__ bsum) {
  __shared__ int s[256];
  const int t = threadIdx.x;
  const int i = blockIdx.x * 256 + t;
  const int v = cntT[i];
  s[t] = v;
  __syncthreads();
  #pragma unroll
  for (int off = 1; off < 256; off <<= 1) {
    const int x = (t >= off) ? s[t - off] : 0;
    __syncthreads();
    s[t] += x;
    __syncthreads();
  }
  offsT[i] = s[t] - v;
  if (t == 255) bsum[blockIdx.x] = s[255];
}

// ---------------- K3: scan bucket totals -> global bucket starts ----------------
__global__ __launch_bounds__(1024) void k_scan_b(const int* __restrict__ bsum,
                                                 int* __restrict__ bsum2) {
  __shared__ int s[1024];
  const int t = threadIdx.x;
  const int v = (t < NBUK) ? bsum[t] : 0;
  s[t] = v;
  __syncthreads();
  #pragma unroll
  for (int off = 1; off < 1024; off <<= 1) {
    const int x = (t >= off) ? s[t - off] : 0;
    __syncthreads();
    s[t] += x;
    __syncthreads();
  }
  if (t < NBUK) bsum2[t] = s[t] - v;
  if (t == NBUK) bsum2[NBUK] = EE;
}

// ---------------- K4: private counting-sort scatter ----------------
__global__ __launch_bounds__(256) void k_scatter(const int* __restrict__ esrc,
                                                 const int* __restrict__ edst,
                                                 const int* __restrict__ etyp,
                                                 const float* __restrict__ enorm,
                                                 const int* __restrict__ offsT,
                                                 const int* __restrict__ bsum2,
                                                 uint2* __restrict__ rec) {
  __shared__ int cur[NBUK];
  const int bl = blockIdx.x, tid = threadIdx.x;
  for (int i = tid; i < NBUK; i += 256) cur[i] = offsT[i * NBLK + bl] + bsum2[i];
  __syncthreads();
  const int e0 = bl * EPB, e1 = min(EE, e0 + EPB);
  for (int e = e0 + tid; e < e1; e += 256) {
    const int d = edst[e];
    const int pos = atomicAdd(&cur[d >> BSH], 1);
    // pack: (typ*NN+src)<<6 | dstlow  (r.x>>6 == X row id, typ-major layout)
    rec[pos] = make_uint2(((unsigned)(etyp[e] * NN + esrc[e]) << 6) | (unsigned)(d & 63),
                          __float_as_uint(enorm[e]));
  }
}

// ---------------- K5: in-bucket sort by exact dst node (in place) ----------------
__global__ __launch_bounds__(256) void k_nsort(const int* __restrict__ bsum2,
                                               uint2* __restrict__ rec,
                                               int* __restrict__ noffs) {
  __shared__ uint2 sbuf[SCAP];  // 16 KB
  __shared__ int cnt[64], cur[64];
  const int bu = blockIdx.x, tid = threadIdx.x;
  const int s = bsum2[bu];
  const int e = bsum2[bu + 1];
  const int n = e - s;
  if (tid < 64) cnt[tid] = 0;
  __syncthreads();
  if (n > SCAP) {  // ~impossible overflow: leave unsorted, mark for slow gather
    if (tid < 64) noffs[(bu << BSH) + tid] = -1;
    return;
  }
  for (int i = tid; i < n; i += 256) {
    const uint2 r = rec[s + i];
    sbuf[i] = r;
    atomicAdd(&cnt[r.x & 63u], 1);
  }
  __syncthreads();
  if (tid < 64) {
    const int v = cnt[tid];
    int x = v;
    #pragma unroll
    for (int off = 1; off < 64; off <<= 1) {
      const int t = __shfl_up(x, off, 64);
      if (tid >= off) x += t;
    }
    cur[tid] = x - v;
    noffs[(bu << BSH) + tid] = s + x - v;
  }
  __syncthreads();
  for (int i = tid; i < n; i += 256) {
    const uint2 r = sbuf[i];
    const int pos = atomicAdd(&cur[r.x & 63u], 1);
    rec[s + pos] = r;
  }
}

// ---------------- K6: wave-per-node gather, rec-prefetch + shfl, unroll-4 ----------------
__global__ __launch_bounds__(256) void k_ngather(const uint2* __restrict__ rec,
                                                 const int* __restrict__ noffs,
                                                 const int* __restrict__ bsum2,
                                                 const unsigned short* __restrict__ X,
                                                 const float* __restrict__ bias,
                                                 float* __restrict__ out) {
  const int w = (int)((blockIdx.x * 256 + threadIdx.x) >> 6);  // node id
  const int lane = threadIdx.x & 63;
  if (w >= NN) return;
  const int quarter = lane >> 4, d4 = lane & 15;
  const int bu = w >> BSH;
  float4 acc = {0.f, 0.f, 0.f, 0.f};
  const int jb = noffs[w];
  if (jb >= 0) {
    const int je = ((w & 63) == 63) ? bsum2[bu + 1] : noffs[w + 1];
    for (int base = jb; base < je; base += 64) {
      const int deg = min(64, je - base);
      unsigned rxs = 0;
      float rns = 0.f;
      if (lane < deg) {
        const uint2 r = rec[base + lane];
        rxs = r.x >> 6;
        rns = __uint_as_float(r.y);
      }
      int u = 0;
      for (; u + 16 <= deg; u += 16) {  // 16 edges per body, 4 independent X loads
        unsigned row[4];
        float nm[4];
        uint2 xv[4];
        #pragma unroll
        for (int k = 0; k < 4; ++k) {
          const int i = u + 4 * k + quarter;
          row[k] = (unsigned)__shfl((int)rxs, i, 64);
          nm[k] = __shfl(rns, i, 64);
        }
        #pragma unroll
        for (int k = 0; k < 4; ++k)
          xv[k] = *reinterpret_cast<const uint2*>(X + (size_t)row[k] * 64 + (d4 << 2));
        #pragma unroll
        for (int k = 0; k < 4; ++k) {
          acc.x = fmaf(nm[k], bf2f((unsigned short)(xv[k].x & 0xffffu)), acc.x);
          acc.y = fmaf(nm[k], bf2f((unsigned short)(xv[k].x >> 16)), acc.y);
          acc.z = fmaf(nm[k], bf2f((unsigned short)(xv[k].y & 0xffffu)), acc.z);
          acc.w = fmaf(nm[k], bf2f((unsigned short)(xv[k].y >> 16)), acc.w);
        }
      }
      for (; u + 8 <= deg; u += 8) {
        const int i0 = u + quarter, i1 = u + 4 + quarter;
        const unsigned row0 = (unsigned)__shfl((int)rxs, i0, 64);
        const float n0 = __shfl(rns, i0, 64);
        const unsigned row1 = (unsigned)__shfl((int)rxs, i1, 64);
        const float n1 = __shfl(rns, i1, 64);
        const uint2 x0 = *reinterpret_cast<const uint2*>(X + (size_t)row0 * 64 + (d4 << 2));
        const uint2 x1 = *reinterpret_cast<const uint2*>(X + (size_t)row1 * 64 + (d4 << 2));
        acc.x = fmaf(n0, bf2f((unsigned short)(x0.x & 0xffffu)), acc.x);
        acc.y = fmaf(n0, bf2f((unsigned short)(x0.x >> 16)), acc.y);
        acc.z = fmaf(n0, bf2f((unsigned short)(x0.y & 0xffffu)), acc.z);
        acc.w = fmaf(n0, bf2f((unsigned short)(x0.y >> 16)), acc.w);
        acc.x = fmaf(n1, bf2f((unsigned short)(x1.x & 0xffffu)), acc.x);
        acc.y = fmaf(n1, bf2f((unsigned short)(x1.x >> 16)), acc.y);
        acc.z = fmaf(n1, bf2f((unsigned short)(x1.y & 0xffffu)), acc.z);
        acc.w = fmaf(n1, bf2f((unsigned short)(x1.y >> 16)), acc.w);
      }
      for (; u < deg; u += 4) {
        const int i = u + quarter;
        const int ic = min(i, deg - 1);
        const unsigned row = (unsigned)__shfl((int)rxs, ic, 64);
        float n = __shfl(rns, ic, 64);
        n = (i < deg) ? n : 0.f;
        const uint2 x = *reinterpret_cast<const uint2*>(X + (size_t)row * 64 + (d4 << 2));
        acc.x = fmaf(n, bf2f((unsigned short)(x.x & 0xffffu)), acc.x);
        acc.y = fmaf(n, bf2f((unsigned short)(x.x >> 16)), acc.y);
        acc.z = fmaf(n, bf2f((unsigned short)(x.y & 0xffffu)), acc.z);
        acc.w = fmaf(n, bf2f((unsigned short)(x.y >> 16)), acc.w);
      }
    }
  } else {
    if (quarter == 0) {
      const int s = bsum2[bu];
      const int e = bsum2[bu + 1];
      const unsigned dl = (unsigned)(w & 63);
      for (int j = s; j < e; ++j) {
        const uint2 r = rec[j];
        if ((r.x & 63u) == dl) {
          const float n = __uint_as_float(r.y);
          const uint2 x =
              *reinterpret_cast<const uint2*>(X + (size_t)(r.x >> 6) * 64 + (d4 << 2));
          acc.x = fmaf(n, bf2f((unsigned short)(x.x & 0xffffu)), acc.x);
          acc.y = fmaf(n, bf2f((unsigned short)(x.x >> 16)), acc.y);
          acc.z = fmaf(n, bf2f((unsigned short)(x.y & 0xffffu)), acc.z);
          acc.w = fmaf(n, bf2f((unsigned short)(x.y >> 16)), acc.w);
        }
      }
    }
  }
  acc.x += __shfl_xor(acc.x, 16, 64);
  acc.y += __shfl_xor(acc.y, 16, 64);
  acc.z += __shfl_xor(acc.z, 16, 64);
  acc.w += __shfl_xor(acc.w, 16, 64);
  acc.x += __shfl_xor(acc.x, 32, 64);
  acc.y += __shfl_xor(acc.y, 32, 64);
  acc.z += __shfl_xor(acc.z, 32, 64);
  acc.w += __shfl_xor(acc.w, 32, 64);
  if (quarter == 0) {
    const float4 b = reinterpret_cast<const float4*>(bias)[d4];
    float4 o;
    o.x = fmaxf(acc.x + b.x, 0.f);
    o.y = fmaxf(acc.y + b.y, 0.f);
    o.z = fmaxf(acc.z + b.z, 0.f);
    o.w = fmaxf(acc.w + b.w, 0.f);
    reinterpret_cast<float4*>(out)[(size_t)w * 16 + d4] = o;
  }
}

extern "C" void kernel_launch(void* const* d_in, const int* in_sizes, int n_in,
                              void* d_out, int out_size, void* d_ws, size_t ws_size,
                              hipStream_t stream) {
  const float* nf = (const float*)d_in[0];
  const int* esrc = (const int*)d_in[1];
  const int* edst = (const int*)d_in[2];
  const int* etyp = (const int*)d_in[3];
  const float* enorm = (const float*)d_in[4];
  const float* W = (const float*)d_in[5];
  const float* bias = (const float*)d_in[6];
  float* out = (float*)d_out;

  char* ws = (char*)d_ws;
  unsigned short* X = (unsigned short*)ws;                 // 102,400,000 B
  unsigned short* Wt = (unsigned short*)(ws + 102400000);  //     131,072 B
  uint2* rec = (uint2*)(ws + 102531072);                   //   8,000,000 B
  int* cntT = (int*)(ws + 110531072);                      //     800,768 B
  int* offsT = (int*)(ws + 111331840);                     //     800,768 B
  int* bsum = (int*)(ws + 112132608);                      //       3,128 B
  int* bsum2 = (int*)(ws + 112135736);                     //       3,132 B
  int* noffs = (int*)(ws + 112138868);                     //     200,192 B

  k_wt<<<RR, 256, 0, stream>>>(W, Wt);
  k_gemm_hist<<<NBLK + NBUK * 4, 256, 0, stream>>>(nf, Wt, edst, X, cntT);
  k_scan_a<<<NS / 256, 256, 0, stream>>>(cntT, offsT, bsum);
  k_scan_b<<<1, 1024, 0, stream>>>(bsum, bsum2);
  k_scatter<<<NBLK, 256, 0, stream>>>(esrc, edst, etyp, enorm, offsT, bsum2, rec);
  k_nsort<<<NBUK, 256, 0, stream>>>(bsum2, rec, noffs);
  k_ngather<<<(NN * 64 + 255) / 256, 256, 0, stream>>>(rec, noffs, bsum2, X, bias, out);
}

// Round 19
// 95.455 us; speedup vs baseline: 15.6555x; 1.0694x over previous
//
#include <hip/hip_runtime.h>
#include <hip/hip_bf16.h>

// RGCN layer, MI355X (gfx950).
// R19 = R18 (best, 102.08us) + nsort/ngather FUSION: sort bucket records in LDS and
// gather straight from LDS -- the 8MB sorted-rec + noffs HBM round-trip and one
// dispatch gap are eliminated. TLP preserved: 782 blocks x 16 waves = 32 waves/CU
// (same as split version); each wave serially gathers 4 nodes with the proven
// rec-prefetch + shfl + unroll-4 body.
//  K0 k_wt | K1 k_gemm_hist (hist 0..255 + gemm, write wall) | K2 k_scan_a |
//  K3 k_scan_b | K4 k_scatter | K5 k_sortgather (fused).
//
// ws: X 102.4MB | Wt 128KB | rec 8MB | cntT 800KB | offsT 800KB | bsum | bsum2

#define NN 50000
#define EE 1000000
#define RR 16
#define NBLK 256            // binning blocks (hist/scatter)
#define EPB 3907            // ceil(EE/NBLK)
#define BSH 6               // 64 nodes per bucket
#define NBUK 782            // ceil(NN/64)
#define NS (NBUK * NBLK)    // 200192
#define SCAP 2048           // bucket LDS record capacity (mean 1279, +21 sigma)

typedef __attribute__((ext_vector_type(8))) short short8;
typedef __attribute__((ext_vector_type(4))) float f32x4;

static __device__ inline unsigned short f2bf(float f) {
  union { __hip_bfloat16 h; unsigned short u; } cv;
  cv.h = __float2bfloat16(f);
  return cv.u;
}
static __device__ inline float bf2f(unsigned short u) {
  union { unsigned i; float f; } cv;
  cv.i = ((unsigned)u) << 16;
  return cv.f;
}

// ---------------- K0: W[r][k][o] fp32 -> Wt[r][o][k] bf16 (one-time) ----------------
__global__ __launch_bounds__(256) void k_wt(const float* __restrict__ W,
                                            unsigned short* __restrict__ Wt) {
  __shared__ __align__(16) unsigned short Wl[64][72];
  const int r = blockIdx.x, tid = threadIdx.x;
  for (int i = tid; i < 4096; i += 256) Wl[i & 63][i >> 6] = f2bf(W[(r << 12) + i]);
  __syncthreads();
  const int o = tid >> 2, kc = (tid & 3) << 4;
  const short8 v0 = *reinterpret_cast<const short8*>(&Wl[o][kc]);
  const short8 v1 = *reinterpret_cast<const short8*>(&Wl[o][kc + 8]);
  unsigned short* dst = Wt + (r << 12) + (o << 6) + kc;
  *reinterpret_cast<short8*>(dst) = v0;
  *reinterpret_cast<short8*>(dst + 8) = v1;
}

// ---------------- K1: fused edge-histogram + dense transform ----------------
__global__ __launch_bounds__(256) void k_gemm_hist(const float* __restrict__ nf,
                                                   const unsigned short* __restrict__ Wt,
                                                   const int* __restrict__ edst,
                                                   unsigned short* __restrict__ X,
                                                   int* __restrict__ cntT) {
  __shared__ __align__(16) char smem[4 * 64 * 72 * 2];  // 36,864 B union
  const int bid = blockIdx.x, tid = threadIdx.x;
  if (bid < NBLK) {
    // ---- histogram path ----
    int* cnt = reinterpret_cast<int*>(smem);
    for (int i = tid; i < NBUK; i += 256) cnt[i] = 0;
    __syncthreads();
    const int e0 = bid * EPB, e1 = min(EE, e0 + EPB);
    for (int e = e0 + tid; e < e1; e += 256) atomicAdd(&cnt[edst[e] >> BSH], 1);
    __syncthreads();
    for (int i = tid; i < NBUK; i += 256) cntT[i * NBLK + bid] = cnt[i];
    return;
  }
  // ---- gemm path ----
  auto Wl = reinterpret_cast<unsigned short(*)[64][72]>(smem);
  const int g = bid - NBLK;
  const int bx = g >> 2, r0 = (g & 3) << 2;
  const int lane = tid & 63, wv = tid >> 6;
  const int lr = lane & 15, lg = lane >> 4;
  const int node = (bx << 6) + (wv << 4) + lr;
  #pragma unroll
  for (int rr = 0; rr < 4; ++rr) {
    const unsigned short* src = Wt + (((size_t)(r0 + rr)) << 12) + (tid << 4);
    const short8 v0 = *reinterpret_cast<const short8*>(src);
    const short8 v1 = *reinterpret_cast<const short8*>(src + 8);
    unsigned short* dst = &Wl[rr][tid >> 2][(tid & 3) << 4];
    *reinterpret_cast<short8*>(dst) = v0;
    *reinterpret_cast<short8*>(dst + 8) = v1;
  }
  short8 bf0, bf1;
  if (node < NN) {
    const float* ap = nf + (size_t)node * 64 + lg * 8;
    float4 v0 = *reinterpret_cast<const float4*>(ap);
    float4 v1 = *reinterpret_cast<const float4*>(ap + 4);
    float4 v2 = *reinterpret_cast<const float4*>(ap + 32);
    float4 v3 = *reinterpret_cast<const float4*>(ap + 36);
    bf0 = short8{(short)f2bf(v0.x), (short)f2bf(v0.y), (short)f2bf(v0.z), (short)f2bf(v0.w),
                 (short)f2bf(v1.x), (short)f2bf(v1.y), (short)f2bf(v1.z), (short)f2bf(v1.w)};
    bf1 = short8{(short)f2bf(v2.x), (short)f2bf(v2.y), (short)f2bf(v2.z), (short)f2bf(v2.w),
                 (short)f2bf(v3.x), (short)f2bf(v3.y), (short)f2bf(v3.z), (short)f2bf(v3.w)};
  } else {
    bf0 = short8{0, 0, 0, 0, 0, 0, 0, 0};
    bf1 = bf0;
  }
  __syncthreads();
  #pragma unroll
  for (int rr = 0; rr < 4; ++rr) {
    const int r = r0 + rr;
    short8 a[8];
    #pragma unroll
    for (int c = 0; c < 4; ++c) {
      a[2 * c] = *reinterpret_cast<const short8*>(&Wl[rr][(c << 4) + lr][lg << 3]);
      a[2 * c + 1] = *reinterpret_cast<const short8*>(&Wl[rr][(c << 4) + lr][32 + (lg << 3)]);
    }
    f32x4 acc[4];
    #pragma unroll
    for (int c = 0; c < 4; ++c) {
      acc[c] = f32x4{0.f, 0.f, 0.f, 0.f};
      acc[c] = __builtin_amdgcn_mfma_f32_16x16x32_bf16(a[2 * c], bf0, acc[c], 0, 0, 0);
      acc[c] = __builtin_amdgcn_mfma_f32_16x16x32_bf16(a[2 * c + 1], bf1, acc[c], 0, 0, 0);
    }
    if (node < NN) {
      #pragma unroll
      for (int c = 0; c < 4; ++c) {
        uint2 p;
        p.x = (unsigned)f2bf(acc[c][0]) | ((unsigned)f2bf(acc[c][1]) << 16);
        p.y = (unsigned)f2bf(acc[c][2]) | ((unsigned)f2bf(acc[c][3]) << 16);
        *reinterpret_cast<uint2*>(&X[((size_t)r * NN + node) * 64 + (c << 4) + (lg << 2)]) = p;
      }
    }
  }
}

// ---------------- K2: per-bucket scan of per-block counts ----------------
__global__ __launch_bounds__(256) void k_scan_a(const int* __restrict__ cntT,
                                                int* __restrict__ offsT,
                                                int* __restrict__ bsum) {
  __shared__ int s[256];
  const int t = threadIdx.x;
  const int i = blockIdx.x * 256 + t;
  const int v = cntT[i];
  s[t] = v;
  __syncthreads();
  #pragma unroll
  for (int off = 1; off < 256; off <<= 1) {
    const int x = (t >= off) ? s[t - off] : 0;
    __syncthreads();
    s[t] += x;
    __syncthreads();
  }
  offsT[i] = s[t] - v;
  if (t == 255) bsum[blockIdx.x] = s[255];
}

// ---------------- K3: scan bucket totals -> global bucket starts ----------------
__global__ __launch_bounds__(1024) void k_scan_b(const int* __restrict__ bsum,
                                                 int* __restrict__ bsum2) {
  __shared__ int s[1024];
  const int t = threadIdx.x;
  const int v = (t < NBUK) ? bsum[t] : 0;
  s[t] = v;
  __syncthreads();
  #pragma unroll
  for (int off = 1; off < 1024; off <<= 1) {
    const int x = (t >= off) ? s[t - off] : 0;
    __syncthreads();
    s[t] += x;
    __syncthreads();
  }
  if (t < NBUK) bsum2[t] = s[t] - v;
  if (t == NBUK) bsum2[NBUK] = EE;
}

// ---------------- K4: private counting-sort scatter ----------------
__global__ __launch_bounds__(256) void k_scatter(const int* __restrict__ esrc,
                                                 const int* __restrict__ edst,
                                                 const int* __restrict__ etyp,
                                                 const float* __restrict__ enorm,
                                                 const int* __restrict__ offsT,
                                                 const int* __restrict__ bsum2,
                                                 uint2* __restrict__ rec) {
  __shared__ int cur[NBUK];
  const int bl = blockIdx.x, tid = threadIdx.x;
  for (int i = tid; i < NBUK; i += 256) cur[i] = offsT[i * NBLK + bl] + bsum2[i];
  __syncthreads();
  const int e0 = bl * EPB, e1 = min(EE, e0 + EPB);
  for (int e = e0 + tid; e < e1; e += 256) {
    const int d = edst[e];
    const int pos = atomicAdd(&cur[d >> BSH], 1);
    // pack: (typ*NN+src)<<6 | dstlow  (r.x>>6 == X row id, typ-major layout)
    rec[pos] = make_uint2(((unsigned)(etyp[e] * NN + esrc[e]) << 6) | (unsigned)(d & 63),
                          __float_as_uint(enorm[e]));
  }
}

// ---------------- K5: fused in-LDS node sort + gather + bias + relu ----------------
// Block = 1024 thr / 16 waves per bucket. Sort bucket records into sbuf2 (LDS
// counting sort by dst&63); wave wv gathers nodes wv*4..wv*4+3 straight from LDS.
__global__ __launch_bounds__(1024) void k_sortgather(const int* __restrict__ bsum2,
                                                     const uint2* __restrict__ rec,
                                                     const unsigned short* __restrict__ X,
                                                     const float* __restrict__ bias,
                                                     float* __restrict__ out) {
  __shared__ uint2 sbuf[SCAP];   // 16 KB raw
  __shared__ uint2 sbuf2[SCAP];  // 16 KB node-sorted
  __shared__ int cnt[64], cur[64], nstart[65];
  const int bu = blockIdx.x, tid = threadIdx.x;
  const int s = bsum2[bu];
  const int e = bsum2[bu + 1];
  const int n = e - s;
  const int lane = tid & 63, wv = tid >> 6;
  const int quarter = lane >> 4, d4 = lane & 15;
  if (tid < 64) cnt[tid] = 0;
  __syncthreads();
  const bool sorted = (n <= SCAP);
  if (sorted) {
    for (int i = tid; i < n; i += 1024) {
      const uint2 r = rec[s + i];
      sbuf[i] = r;
      atomicAdd(&cnt[r.x & 63u], 1);  // native ds_add_u32
    }
    __syncthreads();
    if (tid < 64) {  // wave-0 shfl exclusive scan of 64 bins
      const int v = cnt[tid];
      int x = v;
      #pragma unroll
      for (int off = 1; off < 64; off <<= 1) {
        const int t = __shfl_up(x, off, 64);
        if (tid >= off) x += t;
      }
      cur[tid] = x - v;
      nstart[tid] = x - v;
      if (tid == 63) nstart[64] = n;
    }
    __syncthreads();
    for (int i = tid; i < n; i += 1024) {
      const uint2 r = sbuf[i];
      const int pos = atomicAdd(&cur[r.x & 63u], 1);
      sbuf2[pos] = r;
    }
    __syncthreads();
  }
  // gather: wave wv owns local nodes wv*4 .. wv*4+3 (no barriers below)
  #pragma unroll
  for (int k = 0; k < 4; ++k) {
    const int nl = (wv << 2) + k;
    const int w = (bu << BSH) + nl;
    float4 acc = {0.f, 0.f, 0.f, 0.f};
    if (sorted) {
      const int jb = nstart[nl], je = nstart[nl + 1];
      for (int base = jb; base < je; base += 64) {
        const int deg = min(64, je - base);
        unsigned rxs = 0;
        float rns = 0.f;
        if (lane < deg) {
          const uint2 r = sbuf2[base + lane];
          rxs = r.x >> 6;
          rns = __uint_as_float(r.y);
        }
        int u = 0;
        for (; u + 16 <= deg; u += 16) {  // 16 edges per body, 4 independent X loads
          unsigned row[4];
          float nm[4];
          uint2 xv[4];
          #pragma unroll
          for (int q = 0; q < 4; ++q) {
            const int i = u + 4 * q + quarter;
            row[q] = (unsigned)__shfl((int)rxs, i, 64);
            nm[q] = __shfl(rns, i, 64);
          }
          #pragma unroll
          for (int q = 0; q < 4; ++q)
            xv[q] = *reinterpret_cast<const uint2*>(X + (size_t)row[q] * 64 + (d4 << 2));
          #pragma unroll
          for (int q = 0; q < 4; ++q) {
            acc.x = fmaf(nm[q], bf2f((unsigned short)(xv[q].x & 0xffffu)), acc.x);
            acc.y = fmaf(nm[q], bf2f((unsigned short)(xv[q].x >> 16)), acc.y);
            acc.z = fmaf(nm[q], bf2f((unsigned short)(xv[q].y & 0xffffu)), acc.z);
            acc.w = fmaf(nm[q], bf2f((unsigned short)(xv[q].y >> 16)), acc.w);
          }
        }
        for (; u + 8 <= deg; u += 8) {
          const int i0 = u + quarter, i1 = u + 4 + quarter;
          const unsigned row0 = (unsigned)__shfl((int)rxs, i0, 64);
          const float n0 = __shfl(rns, i0, 64);
          const unsigned row1 = (unsigned)__shfl((int)rxs, i1, 64);
          const float n1 = __shfl(rns, i1, 64);
          const uint2 x0 = *reinterpret_cast<const uint2*>(X + (size_t)row0 * 64 + (d4 << 2));
          const uint2 x1 = *reinterpret_cast<const uint2*>(X + (size_t)row1 * 64 + (d4 << 2));
          acc.x = fmaf(n0, bf2f((unsigned short)(x0.x & 0xffffu)), acc.x);
          acc.y = fmaf(n0, bf2f((unsigned short)(x0.x >> 16)), acc.y);
          acc.z = fmaf(n0, bf2f((unsigned short)(x0.y & 0xffffu)), acc.z);
          acc.w = fmaf(n0, bf2f((unsigned short)(x0.y >> 16)), acc.w);
          acc.x = fmaf(n1, bf2f((unsigned short)(x1.x & 0xffffu)), acc.x);
          acc.y = fmaf(n1, bf2f((unsigned short)(x1.x >> 16)), acc.y);
          acc.z = fmaf(n1, bf2f((unsigned short)(x1.y & 0xffffu)), acc.z);
          acc.w = fmaf(n1, bf2f((unsigned short)(x1.y >> 16)), acc.w);
        }
        for (; u < deg; u += 4) {
          const int i = u + quarter;
          const int ic = min(i, deg - 1);
          const unsigned row = (unsigned)__shfl((int)rxs, ic, 64);
          float nm = __shfl(rns, ic, 64);
          nm = (i < deg) ? nm : 0.f;
          const uint2 x = *reinterpret_cast<const uint2*>(X + (size_t)row * 64 + (d4 << 2));
          acc.x = fmaf(nm, bf2f((unsigned short)(x.x & 0xffffu)), acc.x);
          acc.y = fmaf(nm, bf2f((unsigned short)(x.x >> 16)), acc.y);
          acc.z = fmaf(nm, bf2f((unsigned short)(x.y & 0xffffu)), acc.z);
          acc.w = fmaf(nm, bf2f((unsigned short)(x.y >> 16)), acc.w);
        }
      }
    } else if (quarter == 0) {
      // ~impossible oversized bucket: filter-scan global rec
      const unsigned dl = (unsigned)nl;
      for (int j = s; j < e; ++j) {
        const uint2 r = rec[j];
        if ((r.x & 63u) == dl) {
          const float nm = __uint_as_float(r.y);
          const uint2 x =
              *reinterpret_cast<const uint2*>(X + (size_t)(r.x >> 6) * 64 + (d4 << 2));
          acc.x = fmaf(nm, bf2f((unsigned short)(x.x & 0xffffu)), acc.x);
          acc.y = fmaf(nm, bf2f((unsigned short)(x.x >> 16)), acc.y);
          acc.z = fmaf(nm, bf2f((unsigned short)(x.y & 0xffffu)), acc.z);
          acc.w = fmaf(nm, bf2f((unsigned short)(x.y >> 16)), acc.w);
        }
      }
    }
    acc.x += __shfl_xor(acc.x, 16, 64);
    acc.y += __shfl_xor(acc.y, 16, 64);
    acc.z += __shfl_xor(acc.z, 16, 64);
    acc.w += __shfl_xor(acc.w, 16, 64);
    acc.x += __shfl_xor(acc.x, 32, 64);
    acc.y += __shfl_xor(acc.y, 32, 64);
    acc.z += __shfl_xor(acc.z, 32, 64);
    acc.w += __shfl_xor(acc.w, 32, 64);
    if (quarter == 0 && w < NN) {
      const float4 b = reinterpret_cast<const float4*>(bias)[d4];
      float4 o;
      o.x = fmaxf(acc.x + b.x, 0.f);
      o.y = fmaxf(acc.y + b.y, 0.f);
      o.z = fmaxf(acc.z + b.z, 0.f);
      o.w = fmaxf(acc.w + b.w, 0.f);
      reinterpret_cast<float4*>(out)[(size_t)w * 16 + d4] = o;
    }
  }
}

extern "C" void kernel_launch(void* const* d_in, const int* in_sizes, int n_in,
                              void* d_out, int out_size, void* d_ws, size_t ws_size,
                              hipStream_t stream) {
  const float* nf = (const float*)d_in[0];
  const int* esrc = (const int*)d_in[1];
  const int* edst = (const int*)d_in[2];
  const int* etyp = (const int*)d_in[3];
  const float* enorm = (const float*)d_in[4];
  const float* W = (const float*)d_in[5];
  const float* bias = (const float*)d_in[6];
  float* out = (float*)d_out;

  char* ws = (char*)d_ws;
  unsigned short* X = (unsigned short*)ws;                 // 102,400,000 B
  unsigned short* Wt = (unsigned short*)(ws + 102400000);  //     131,072 B
  uint2* rec = (uint2*)(ws + 102531072);                   //   8,000,000 B
  int* cntT = (int*)(ws + 110531072);                      //     800,768 B
  int* offsT = (int*)(ws + 111331840);                     //     800,768 B
  int* bsum = (int*)(ws + 112132608);                      //       3,128 B
  int* bsum2 = (int*)(ws + 112135736);                     //       3,132 B

  k_wt<<<RR, 256, 0, stream>>>(W, Wt);
  k_gemm_hist<<<NBLK + NBUK * 4, 256, 0, stream>>>(nf, Wt, edst, X, cntT);
  k_scan_a<<<NS / 256, 256, 0, stream>>>(cntT, offsT, bsum);
  k_scan_b<<<1, 1024, 0, stream>>>(bsum, bsum2);
  k_scatter<<<NBLK, 256, 0, stream>>>(esrc, edst, etyp, enorm, offsT, bsum2, rec);
  k_sortgather<<<NBUK, 1024, 0, stream>>>(bsum2, rec, X, bias, out);
}